// Round 3
// baseline (470.455 us; speedup 1.0000x reference)
//
#include <hip/hip_runtime.h>

// Shift: out[b,c,h,w] = x[b,c, clamp(h + trunc(ypos[h]*stride), 0, H-1),
//                              clamp(w + trunc(xpos[w]*stride), 0, W-1)]
// B=16, C=64, H=256, W=256, fp32.
//
// sh is row-uniform. For the w-gather, take a per-group fast path: if
// trunc(xpos[w]*stride)==0 for all 4 w's of a float4 group (true for the
// bench's xpos ~ U(-1e-8,1e-8)), the group is an aligned contiguous float4
// copy from the (shifted) source row. Fallback: scalar clamped gather.
// Result: pure streaming copy — 1 float4 load + 1 float4 store per 4 elems,
// no LDS, no barrier, max occupancy.

constexpr int Bc = 16;
constexpr int Cc = 64;
constexpr int Hc = 256;
constexpr int Wc = 256;

__global__ __launch_bounds__(256) void shift_kernel(
    const float* __restrict__ x,
    const float* __restrict__ xpos,
    const float* __restrict__ ypos,
    const int* __restrict__ stride_p,
    float* __restrict__ out)
{
    const int stride = *stride_p;
    const float fs = (float)stride;

    // 8 elements (two float4 groups) per thread; 32 threads cover one row.
    const long long tid = (long long)blockIdx.x * blockDim.x + threadIdx.x;
    const int w0 = (int)(tid & 31) * 8;
    const long long rowIdx = tid >> 5;          // b*C*H + c*H + h
    const int h = (int)(rowIdx & (Hc - 1));
    const long long plane = rowIdx >> 8;        // b*C + c

    int sh = h + (int)(ypos[h] * fs);           // row-uniform, trunc toward zero
    sh = min(max(sh, 0), Hc - 1);

    const float* __restrict__ src = x + (plane * Hc + sh) * (long long)Wc;
    float* __restrict__ dst = out + rowIdx * (long long)Wc;

#pragma unroll
    for (int g = 0; g < 2; ++g) {
        const int wg = w0 + 4 * g;
        const float4 xp = *reinterpret_cast<const float4*>(xpos + wg);
        const int d0 = (int)(xp.x * fs);
        const int d1 = (int)(xp.y * fs);
        const int d2 = (int)(xp.z * fs);
        const int d3 = (int)(xp.w * fs);

        float4 v;
        if ((d0 | d1 | d2 | d3) == 0) {
            // sw == w for all four: aligned contiguous copy from shifted row
            v = *reinterpret_cast<const float4*>(src + wg);
        } else {
            const int d[4] = {d0, d1, d2, d3};
            float r[4];
#pragma unroll
            for (int i = 0; i < 4; ++i) {
                int sw = wg + i + d[i];
                sw = min(max(sw, 0), Wc - 1);
                r[i] = src[sw];
            }
            v = make_float4(r[0], r[1], r[2], r[3]);
        }
        *reinterpret_cast<float4*>(dst + wg) = v;
    }
}

extern "C" void kernel_launch(void* const* d_in, const int* in_sizes, int n_in,
                              void* d_out, int out_size, void* d_ws, size_t ws_size,
                              hipStream_t stream)
{
    const float* x    = (const float*)d_in[0];
    const float* xpos = (const float*)d_in[1];
    const float* ypos = (const float*)d_in[2];
    const int* stride = (const int*)d_in[3];
    float* out        = (float*)d_out;

    const long long total_threads = (long long)Bc * Cc * Hc * (Wc / 8);  // 8.4M
    const int block = 256;
    const int grid = (int)(total_threads / block);                       // 32768

    shift_kernel<<<grid, block, 0, stream>>>(x, xpos, ypos, stride, out);
}